// Round 6
// 1351.385 us; speedup vs baseline: 1.3355x; 1.3355x over previous
//
#include <hip/hip_runtime.h>
#include <math.h>

#define ROW_FEAT 256
#define BT 512
#define WAVES 8
#define RPW 4                    // rows per wave
#define PERBLK (WAVES * RPW)     // 32 rows per block per iteration

// 14 panels of 64x64 fp16 weights, b64-packed:
//   panel p, dword-pair index (u>>2)*64 + c  holds halfs W[4*(u>>2)+k][c], k=0..3
// so ds_read_b64 at ((u4*64 + lane) * 4 halfs) yields weights for 4 consecutive
// u at column `lane`. Weight LDS is written once, __syncthreads, then read-only:
// there is NO LDS write->read round-trip in the main loop (the structure that
// produced rounds 1-5's irreproducible corruption is gone entirely).
#define PANEL_HALFS 4096
#define NPANEL 14
#define W_HALFS (NPANEL * PANEL_HALFS)   // 57344
#define SMEM_BYTES (W_HALFS * 2)         // 114688

typedef __fp16 f16 __attribute__((may_alias));
typedef __fp16 h4_b __attribute__((ext_vector_type(4)));
typedef h4_b h4 __attribute__((may_alias));

// wave-uniform lane broadcast through the register crossbar (no memory)
__device__ __forceinline__ float rl(float v, int u) {
    return __uint_as_float(__builtin_amdgcn_readlane(__float_as_uint(v), u));
}

#define LDP(p, u4) (*(const h4*)(wh + (p) * PANEL_HALFS + ((((u4) << 6) + lane) << 2)))

__global__ __launch_bounds__(BT, 2)
void tp_gemv(const float* __restrict__ x, const float* __restrict__ y,
             const float* __restrict__ scalars,
             const float* __restrict__ W1, const float* __restrict__ W2,
             const float* __restrict__ W3, const float* __restrict__ W4,
             const float* __restrict__ Wm1, const float* __restrict__ Wm2,
             const float* __restrict__ Wm3, const float* __restrict__ Wl0,
             const float* __restrict__ Wl1,
             float* __restrict__ out, int nrows, float silu_cst)
{
    extern __shared__ char smem[];
    f16* wh = (f16*)smem;
    const int tid = threadIdx.x;

    // ---- stage weights into LDS as b64-packed fp16 panels ----
    {
        const float* srcs[NPANEL] = {W1, W2, W3, W4, Wm1, Wm2,
                                     Wm3, Wm3, Wm3, Wm3, Wl0, Wl0, Wl1, Wl1};
        const int strd[NPANEL] = {64,64,64,64,64,64, 256,256,256,256, 64,64,64,64};
        const int uoff[NPANEL] = {0,0,0,0,0,0, 0,0,0,0, 0,64,0,64};
        const int coff[NPANEL] = {0,0,0,0,0,0, 0,64,128,192, 0,0,0,0};
        for (int p = 0; p < NPANEL; ++p) {
            const float* s = srcs[p];
            f16* d = wh + p * PANEL_HALFS;
            const int st = strd[p], uo = uoff[p], co = coff[p];
            for (int idx = tid; idx < PANEL_HALFS; idx += BT) {
                const int u = idx >> 6, c = idx & 63;
                d[((((u >> 2) << 6) + c) << 2) + (u & 3)] =
                    (f16)s[(size_t)(u + uo) * st + c + co];
            }
        }
    }
    __syncthreads();   // weights read-only from here on

    const int lane = tid & 63, wave = tid >> 6;

    const float s1    = 0.125f;                  // 1/sqrt(64)
    const float s2c   = 0.07216878364870323f;    // 1/sqrt(192)
    const float lin_s = 0.08838834764831845f;    // 1/sqrt(128)
    const float inv8  = 0.125f;
    const float fg0 = s1 * inv8, fg1 = s2c * inv8;

    for (int base = blockIdx.x * PERBLK + wave * RPW; base < nrows;
         base += gridDim.x * PERBLK) {

        // ---- load activations: lane owns feature index u = lane, RPW rows ----
        float x0[RPW], xa[RPW], xb[RPW], xc[RPW], t0[RPW], sv[RPW];
        float y0[RPW], y1a[RPW], y1b[RPW], y1c[RPW];
        bool ok[RPW];
        #pragma unroll
        for (int r = 0; r < RPW; ++r) {
            const int row = base + r;
            ok[r] = row < nrows;                 // wave-uniform
            const float* xr = x + (size_t)row * ROW_FEAT;
            x0[r] = ok[r] ? xr[lane]               : 0.f;
            xa[r] = ok[r] ? xr[64 + 3*lane + 0]    : 0.f;
            xb[r] = ok[r] ? xr[64 + 3*lane + 1]    : 0.f;
            xc[r] = ok[r] ? xr[64 + 3*lane + 2]    : 0.f;
            sv[r] = ok[r] ? scalars[(size_t)row * 64 + lane] : 0.f;
            y0[r]  = ok[r] ? y[(size_t)row * 4 + 0] : 0.f;
            y1a[r] = ok[r] ? y[(size_t)row * 4 + 1] : 0.f;
            y1b[r] = ok[r] ? y[(size_t)row * 4 + 2] : 0.f;
            y1c[r] = ok[r] ? y[(size_t)row * 4 + 3] : 0.f;
            t0[r] = xa[r]*y1a[r] + xb[r]*y1b[r] + xc[r]*y1c[r];
        }

        // ---- phase 1: the four 64x64 contractions (raw, scales folded later) ----
        float d1[RPW] = {}, d2[RPW] = {}, pp[RPW] = {},
              q0[RPW] = {}, q1[RPW] = {}, q2[RPW] = {};
        #pragma unroll 4
        for (int u4 = 0; u4 < 16; ++u4) {
            h4 wv1 = LDP(0, u4), wv2 = LDP(1, u4), wv3 = LDP(2, u4), wv4 = LDP(3, u4);
            #pragma unroll
            for (int k = 0; k < 4; ++k) {
                const int u = 4*u4 + k;
                const float f1 = (float)wv1[k], f2 = (float)wv2[k];
                const float f3 = (float)wv3[k], f4 = (float)wv4[k];
                #pragma unroll
                for (int r = 0; r < RPW; ++r) {
                    const float a0 = rl(x0[r], u), at = rl(t0[r], u);
                    const float aa = rl(xa[r], u), ab = rl(xb[r], u), ac = rl(xc[r], u);
                    d1[r] = fmaf(a0, f1, d1[r]);
                    d2[r] = fmaf(at, f2, d2[r]);
                    pp[r] = fmaf(a0, f3, pp[r]);
                    q0[r] = fmaf(aa, f4, q0[r]);
                    q1[r] = fmaf(ab, f4, q1[r]);
                    q2[r] = fmaf(ac, f4, q2[r]);
                }
            }
        }

        // ---- MLP layer 1 ----
        float h1[RPW];
        {
            float acc[RPW] = {};
            #pragma unroll 4
            for (int u4 = 0; u4 < 16; ++u4) {
                h4 wv = LDP(4, u4);
                #pragma unroll
                for (int k = 0; k < 4; ++k) {
                    const int u = 4*u4 + k; const float f = (float)wv[k];
                    #pragma unroll
                    for (int r = 0; r < RPW; ++r)
                        acc[r] = fmaf(rl(sv[r], u), f, acc[r]);
                }
            }
            #pragma unroll
            for (int r = 0; r < RPW; ++r) {
                const float tt = acc[r] * inv8;
                h1[r] = tt / (1.f + __expf(-tt)) * silu_cst;
            }
        }

        // ---- MLP layer 2 ----
        float h2[RPW];
        {
            float acc[RPW] = {};
            #pragma unroll 4
            for (int u4 = 0; u4 < 16; ++u4) {
                h4 wv = LDP(5, u4);
                #pragma unroll
                for (int k = 0; k < 4; ++k) {
                    const int u = 4*u4 + k; const float f = (float)wv[k];
                    #pragma unroll
                    for (int r = 0; r < RPW; ++r)
                        acc[r] = fmaf(rl(h1[r], u), f, acc[r]);
                }
            }
            #pragma unroll
            for (int r = 0; r < RPW; ++r) {
                const float tt = acc[r] * inv8;
                h2[r] = tt / (1.f + __expf(-tt)) * silu_cst;
            }
        }

        // ---- MLP layer 3: wts (raw h2 @ Wm3; inv8 folded into fg*/later) ----
        float wa0[RPW] = {}, wa1[RPW] = {}, wa2[RPW] = {}, wa3[RPW] = {};
        #pragma unroll 2
        for (int u4 = 0; u4 < 16; ++u4) {
            h4 w0v = LDP(6, u4), w1v = LDP(7, u4), w2v = LDP(8, u4), w3v = LDP(9, u4);
            #pragma unroll
            for (int k = 0; k < 4; ++k) {
                const int u = 4*u4 + k;
                const float f0 = (float)w0v[k], f1 = (float)w1v[k];
                const float f2 = (float)w2v[k], f3 = (float)w3v[k];
                #pragma unroll
                for (int r = 0; r < RPW; ++r) {
                    const float a = rl(h2[r], u);
                    wa0[r] = fmaf(a, f0, wa0[r]);
                    wa1[r] = fmaf(a, f1, wa1[r]);
                    wa2[r] = fmaf(a, f2, wa2[r]);
                    wa3[r] = fmaf(a, f3, wa3[r]);
                }
            }
        }

        // ---- scaled mids (per lane = feature u of the output GEMVs) ----
        float scA[RPW], scB[RPW], pw[RPW], qw0[RPW], qw1[RPW], qw2[RPW];
        #pragma unroll
        for (int r = 0; r < RPW; ++r) {
            scA[r] = fg0 * y0[r] * d1[r] * wa0[r];   // out0a * w0  (cols 0..63)
            scB[r] = fg1 * d2[r] * wa1[r];           // out0b * w0  (cols 64..127)
            pw[r]  = inv8 * pp[r] * wa2[r];          // p * w1a
            qw0[r] = inv8 * q0[r] * wa3[r];          // q_i * w1b
            qw1[r] = inv8 * q1[r] * wa3[r];
            qw2[r] = inv8 * q2[r] * wa3[r];
        }

        // ---- output layer ----
        float o0[RPW] = {}, r0[RPW] = {}, rq0[RPW] = {}, rq1[RPW] = {}, rq2[RPW] = {};
        #pragma unroll 2
        for (int u4 = 0; u4 < 16; ++u4) {
            h4 la0 = LDP(10, u4), lb0 = LDP(11, u4), la1 = LDP(12, u4), lb1 = LDP(13, u4);
            #pragma unroll
            for (int k = 0; k < 4; ++k) {
                const int u = 4*u4 + k;
                const float fa0 = (float)la0[k], fb0 = (float)lb0[k];
                const float fa1 = (float)la1[k], fb1 = (float)lb1[k];
                #pragma unroll
                for (int r = 0; r < RPW; ++r) {
                    o0[r]  = fmaf(rl(scA[r], u), fa0, o0[r]);
                    o0[r]  = fmaf(rl(scB[r], u), fb0, o0[r]);
                    r0[r]  = fmaf(rl(pw[r],  u), fa1, r0[r]);
                    rq0[r] = fmaf(rl(qw0[r], u), fb1, rq0[r]);
                    rq1[r] = fmaf(rl(qw1[r], u), fb1, rq1[r]);
                    rq2[r] = fmaf(rl(qw2[r], u), fb1, rq2[r]);
                }
            }
        }

        // ---- epilogue (identical math to the verified round-0 baseline) ----
        const float cc = lin_s * s1;
        #pragma unroll
        for (int r = 0; r < RPW; ++r) {
            if (!ok[r]) continue;
            float* orow = out + (size_t)(base + r) * ROW_FEAT;
            orow[lane] = lin_s * o0[r];
            orow[64 + 3*lane + 0] = cc * (y1a[r] * r0[r] + y0[r] * rq0[r]);
            orow[64 + 3*lane + 1] = cc * (y1b[r] * r0[r] + y0[r] * rq1[r]);
            orow[64 + 3*lane + 2] = cc * (y1c[r] * r0[r] + y0[r] * rq2[r]);
        }
    }
}

extern "C" void kernel_launch(void* const* d_in, const int* in_sizes, int n_in,
                              void* d_out, int out_size, void* d_ws, size_t ws_size,
                              hipStream_t stream)
{
    (void)n_in; (void)d_ws; (void)ws_size; (void)out_size;
    const float* x       = (const float*)d_in[0];
    const float* y       = (const float*)d_in[1];
    const float* scalars = (const float*)d_in[2];
    const float* W1  = (const float*)d_in[3];
    const float* W2  = (const float*)d_in[4];
    const float* W3  = (const float*)d_in[5];
    const float* W4  = (const float*)d_in[6];
    const float* Wm1 = (const float*)d_in[7];
    const float* Wm2 = (const float*)d_in[8];
    const float* Wm3 = (const float*)d_in[9];
    const float* Wl0 = (const float*)d_in[10];
    const float* Wl1 = (const float*)d_in[11];
    float* out = (float*)d_out;
    const int nrows = in_sizes[0] / ROW_FEAT;

    // SILU_CST = 1/sqrt(E[silu(z)^2]), z~N(0,1). Simpson over [-13,13]
    // matches the reference's 201-pt Gauss-Hermite to ~1e-9.
    double a = -13.0, bb = 13.0;
    const int nst = 4096;
    double h = (bb - a) / nst, sum = 0.0;
    for (int i = 0; i <= nst; i++) {
        double z = a + i * h;
        double sig = 1.0 / (1.0 + exp(-z));
        double sl = z * sig;
        double f = sl * sl * exp(-0.5 * z * z);
        double w = (i == 0 || i == nst) ? 1.0 : ((i & 1) ? 4.0 : 2.0);
        sum += w * f;
    }
    sum *= h / 3.0 / sqrt(2.0 * M_PI);
    const float silu_cst = (float)(1.0 / sqrt(sum));

    hipFuncSetAttribute(reinterpret_cast<const void*>(tp_gemv),
                        hipFuncAttributeMaxDynamicSharedMemorySize, SMEM_BYTES);
    tp_gemv<<<256, BT, SMEM_BYTES, stream>>>(
        x, y, scalars, W1, W2, W3, W4, Wm1, Wm2, Wm3, Wl0, Wl1,
        out, nrows, silu_cst);
}